// Round 5
// baseline (947.780 us; speedup 1.0000x reference)
//
#include <hip/hip_runtime.h>
#include <hip/hip_bf16.h>

// GCN encoder, reassociated:  out = Y4^T · emb[x] · W^4 + bias terms,
// where Y4 = (A^T)^4 S (S = one-hot columns of the 64 selected nodes).
// Replaces 4x{128-wide agg + 128x128 GEMM} with 4x{64-wide SpMM} + tiny GEMMs.
// Bias kept exact: out += sum_k colsum(Y_k)[g] * (b^T W^k)[d] + b[d]  (zero here but general).
// R4: resubmit of R3 (infra timeout, never measured).

#define D 128
#define NG 64   // graphs in batch (B)

// ---- fused degree histograms: degd (by dst, for norm), degs (by src, for CSR) ----
__global__ void hist2_kernel(const int* __restrict__ src, const int* __restrict__ dst,
                             int* __restrict__ degd, int* __restrict__ degs, int E) {
    int e = blockIdx.x * blockDim.x + threadIdx.x;
    if (e < E) { atomicAdd(&degd[dst[e]], 1); atomicAdd(&degs[src[e]], 1); }
}

// ---- deg_inv_sqrt (GCN norm uses in-degree by dst) ----
__global__ void dis_kernel(const int* __restrict__ degd, float* __restrict__ dis, int n) {
    int i = blockIdx.x * blockDim.x + threadIdx.x;
    if (i < n) {
        int d = degd[i];
        dis[i] = (d > 0) ? rsqrtf((float)d) : 0.0f;
    }
}

__device__ __forceinline__ int wave_incl_scan(int v, int lane) {
    #pragma unroll
    for (int off = 1; off < 64; off <<= 1) {
        int t = __shfl_up(v, off);
        if (lane >= off) v += t;
    }
    return v;
}

// ---- 3-stage exclusive scan of degs -> srow_ptr ----
__global__ __launch_bounds__(256) void scan_reduce(const int* __restrict__ deg,
                                                   int* __restrict__ bsum, int n) {
    __shared__ int wsum[4];
    int b = blockIdx.x, tid = threadIdx.x;
    int s = 0;
    for (int j = tid; j < 1024; j += 256) {
        int idx = b * 1024 + j;
        if (idx < n) s += deg[idx];
    }
    #pragma unroll
    for (int off = 32; off; off >>= 1) s += __shfl_down(s, off);
    int lane = tid & 63, wid = tid >> 6;
    if (lane == 0) wsum[wid] = s;
    __syncthreads();
    if (tid == 0) bsum[b] = wsum[0] + wsum[1] + wsum[2] + wsum[3];
}

__global__ void scan_bsum(const int* __restrict__ bsum, int* __restrict__ boff, int nb) {
    __shared__ int buf[1024];
    int tid = threadIdx.x;
    int v = (tid < nb) ? bsum[tid] : 0;
    buf[tid] = v;
    __syncthreads();
    for (int off = 1; off < 1024; off <<= 1) {
        int t = (tid >= off) ? buf[tid - off] : 0;
        __syncthreads();
        buf[tid] += t;
        __syncthreads();
    }
    if (tid < nb) boff[tid] = buf[tid] - v;
}

__global__ __launch_bounds__(256) void scan_final(const int* __restrict__ deg,
                                                  const int* __restrict__ boff,
                                                  int* __restrict__ row_ptr, int n) {
    __shared__ int wsum[4];
    int b = blockIdx.x, tid = threadIdx.x;
    int lane = tid & 63, wid = tid >> 6;
    int base = b * 1024 + tid * 4;
    int v[4], s = 0;
    #pragma unroll
    for (int j = 0; j < 4; j++) {
        int idx = base + j;
        v[j] = (idx < n) ? deg[idx] : 0;
        s += v[j];
    }
    int incl = wave_incl_scan(s, lane);
    if (lane == 63) wsum[wid] = incl;
    __syncthreads();
    int woff = 0;
    for (int w = 0; w < wid; w++) woff += wsum[w];
    int run = incl - s + woff + boff[b];
    #pragma unroll
    for (int j = 0; j < 4; j++) {
        int idx = base + j;
        run += v[j];
        if (idx < n) row_ptr[idx + 1] = run;
    }
    if (b == 0 && tid == 0) row_ptr[0] = 0;
}

// ---- CSR by SRC (for A^T application); neighbor = dst, weight = dis[src]*dis[dst] ----
__global__ void fill_csr_kernel(const int* __restrict__ src, const int* __restrict__ dst,
                                const float* __restrict__ dis, const int* __restrict__ srow,
                                int* __restrict__ cnt, int* __restrict__ scol,
                                float* __restrict__ senorm, int E) {
    int e = blockIdx.x * blockDim.x + threadIdx.x;
    if (e >= E) return;
    int s = src[e], d = dst[e];
    int pos = srow[s] + atomicAdd(&cnt[s], 1);
    scol[pos] = d;
    senorm[pos] = dis[s] * dis[d];
}

// ---- Y0 init: Y[sel_g, g] = 1 (auto-detect int32/int64 ptr) ----
__global__ void yinit_kernel(const int* __restrict__ ptr32, float* __restrict__ Y) {
    int g = threadIdx.x;   // one block of NG threads
    bool is64 = (ptr32[3] == 0);   // hi word of ptr[1] is 0 iff int64 (ptr[1] > 0)
    long long node;
    if (is64) node = ((const long long*)ptr32)[g + 1] - 1;
    else      node = (long long)ptr32[g + 1] - 1;
    Y[node * NG + g] = 1.0f;
}

// ---- Y_{k+1}[u,:] = sum_{e: src=u} norm_e * Y_k[dst_e,:]  (wave/node, lane=g, 2-edge unroll) ----
__global__ __launch_bounds__(256) void spmm_kernel(const float* __restrict__ Yin,
                                                   const int* __restrict__ srow,
                                                   const int* __restrict__ scol,
                                                   const float* __restrict__ senorm,
                                                   float* __restrict__ Yout, int n) {
    int node = (blockIdx.x * blockDim.x + threadIdx.x) >> 6;
    int g = threadIdx.x & 63;
    if (node >= n) return;
    int beg = srow[node], end = srow[node + 1];
    float a0 = 0.f, a1 = 0.f;
    int j = beg;
    for (; j + 1 < end; j += 2) {
        int s0 = scol[j], s1 = scol[j + 1];
        float w0 = senorm[j], w1 = senorm[j + 1];
        a0 += Yin[(size_t)s0 * NG + g] * w0;
        a1 += Yin[(size_t)s1 * NG + g] * w1;
    }
    if (j < end) a0 += Yin[(size_t)scol[j] * NG + g] * senorm[j];
    Yout[(size_t)node * NG + g] = a0 + a1;
}

// ---- cs[g] += sum_i Y[i,g]  (= A^k 1 at selected nodes) ----
__global__ __launch_bounds__(256) void colsum_kernel(const float* __restrict__ Y,
                                                     float* __restrict__ cs, int n) {
    __shared__ float part[4][64];
    int g = threadIdx.x & 63, w = threadIdx.x >> 6;
    float a = 0.f;
    for (int i = blockIdx.x * 4 + w; i < n; i += gridDim.x * 4)
        a += Y[(size_t)i * NG + g];
    part[w][g] = a;
    __syncthreads();
    if (w == 0) atomicAdd(&cs[g], part[0][g] + part[1][g] + part[2][g] + part[3][g]);
}

// ---- Z[g,d] = sum_i Y4[i,g] * emb[x[i], d]  (embedding folded in; atomics at end) ----
__global__ __launch_bounds__(256) void zacc_kernel(const float* __restrict__ Y,
                                                   const int* __restrict__ x,
                                                   const float* __restrict__ emb,
                                                   float* __restrict__ Z, int n) {
    int g = threadIdx.x >> 2, q = threadIdx.x & 3;   // thread owns (g, d = q*32 .. q*32+31)
    float4 acc[8];
    #pragma unroll
    for (int k = 0; k < 8; k++) acc[k] = make_float4(0.f, 0.f, 0.f, 0.f);
    int chunk = (n + gridDim.x - 1) / gridDim.x;
    int i0 = blockIdx.x * chunk;
    int i1 = min(n, i0 + chunk);
    for (int i = i0; i < i1; i++) {
        int tok = x[i];
        float y = Y[(size_t)i * NG + g];
        const float4* er = (const float4*)(emb + (size_t)tok * D) + q * 8;
        #pragma unroll
        for (int k = 0; k < 8; k++) {
            float4 v = er[k];
            acc[k].x += y * v.x; acc[k].y += y * v.y;
            acc[k].z += y * v.z; acc[k].w += y * v.w;
        }
    }
    float* zp = Z + g * D + q * 32;
    #pragma unroll
    for (int k = 0; k < 8; k++) {
        atomicAdd(zp + k * 4 + 0, acc[k].x);
        atomicAdd(zp + k * 4 + 1, acc[k].y);
        atomicAdd(zp + k * 4 + 2, acc[k].z);
        atomicAdd(zp + k * 4 + 3, acc[k].w);
    }
}

// ---- C = A*A for 128x128 (grid 16, block computes 8 rows; A staged in LDS) ----
__global__ __launch_bounds__(256) void matsq_kernel(const float* __restrict__ A,
                                                    float* __restrict__ C) {
    __shared__ float Al[D * D];
    int tid = threadIdx.x;
    const float4* A4 = (const float4*)A;
    float4* Al4 = (float4*)Al;
    for (int i = tid; i < D * D / 4; i += 256) Al4[i] = A4[i];
    __syncthreads();
    int r = blockIdx.x * 8 + (tid >> 5);
    int c0 = (tid & 31) * 4;
    float4 acc = {0.f, 0.f, 0.f, 0.f};
    for (int k = 0; k < D; k++) {
        float a = Al[r * D + k];
        float4 w = *(const float4*)&Al[k * D + c0];
        acc.x += a * w.x; acc.y += a * w.y; acc.z += a * w.z; acc.w += a * w.w;
    }
    *(float4*)&C[r * D + c0] = acc;
}

// ---- T[k] = b^T W^{k+1}, k=0..2 (one block, 128 threads) ----
__global__ void tvec_kernel(const float* __restrict__ b, const float* __restrict__ W,
                            float* __restrict__ T) {
    __shared__ float cur[D];
    int tid = threadIdx.x;
    cur[tid] = b[tid];
    __syncthreads();
    for (int it = 0; it < 3; it++) {
        float acc = 0.f;
        for (int k = 0; k < D; k++) acc += cur[k] * W[k * D + tid];
        __syncthreads();
        cur[tid] = acc;
        T[it * D + tid] = acc;
        __syncthreads();
    }
}

// ---- out[g,d] = (Z*W4)[g,d] + cs1[g]*T1[d] + cs2[g]*T2[d] + cs3[g]*T3[d] + b[d] ----
__global__ __launch_bounds__(256) void final_kernel(const float* __restrict__ Z,
                                                    const float* __restrict__ W4,
                                                    const float* __restrict__ T,
                                                    const float* __restrict__ cs,
                                                    const float* __restrict__ b,
                                                    float* __restrict__ out) {
    int o = blockIdx.x * blockDim.x + threadIdx.x;
    if (o >= NG * D) return;
    int g = o >> 7, d = o & (D - 1);
    float acc = b[d];
    for (int k = 0; k < D; k++) acc += Z[g * D + k] * W4[k * D + d];
    acc += cs[g] * T[d] + cs[64 + g] * T[D + d] + cs[128 + g] * T[2 * D + d];
    out[o] = acc;
}

extern "C" void kernel_launch(void* const* d_in, const int* in_sizes, int n_in,
                              void* d_out, int out_size, void* d_ws, size_t ws_size,
                              hipStream_t stream) {
    const int*   x    = (const int*)d_in[0];
    const int*   ei   = (const int*)d_in[1];
    const int*   ptr  = (const int*)d_in[2];   // width auto-detected on device
    const float* emb  = (const float*)d_in[4];
    const float* W    = (const float*)d_in[5];
    const float* bias = (const float*)d_in[6];

    const int N = in_sizes[0];
    const int E = in_sizes[1] / 2;

    const int* src = ei;
    const int* dst = ei + E;

    char* ws = (char*)d_ws;
    size_t off = 0;
    auto carve = [&](size_t bytes) -> void* {
        void* p = ws + off;
        off += (bytes + 255) & ~(size_t)255;
        return p;
    };
    float* Ya     = (float*)carve((size_t)N * NG * 4);
    float* Yb     = (float*)carve((size_t)N * NG * 4);
    int*   degd   = (int*)  carve((size_t)N * 4 * 2);   // degd + degs adjacent (one memset)
    int*   degs   = degd + N;
    float* dis    = (float*)carve((size_t)N * 4);
    int*   srow   = (int*)  carve((size_t)(N + 1) * 4);
    int*   cnt    = (int*)  carve((size_t)N * 4);
    int*   scol   = (int*)  carve((size_t)E * 4);
    float* senorm = (float*)carve((size_t)E * 4);
    int    nb     = (N + 1023) / 1024;
    int*   bsum   = (int*)  carve((size_t)nb * 4);
    int*   boff   = (int*)  carve((size_t)nb * 4);
    float* Z      = (float*)carve((size_t)NG * D * 4);  // 32768 B (256-aligned)
    float* cs     = (float*)carve((size_t)3 * NG * 4);  // adjacent to Z
    float* W2     = (float*)carve((size_t)D * D * 4);
    float* W4     = (float*)carve((size_t)D * D * 4);
    float* T      = (float*)carve((size_t)3 * D * 4);

    hipMemsetAsync(degd, 0, (size_t)N * 4 * 2, stream);
    hipMemsetAsync(cnt,  0, (size_t)N * 4, stream);
    hipMemsetAsync(Ya,   0, (size_t)N * NG * 4, stream);
    hipMemsetAsync(Z,    0, (size_t)(NG * D + 3 * NG) * 4, stream);  // Z + cs contiguous

    hist2_kernel<<<(E + 255) / 256, 256, 0, stream>>>(src, dst, degd, degs, E);
    dis_kernel<<<(N + 255) / 256, 256, 0, stream>>>(degd, dis, N);
    scan_reduce<<<nb, 256, 0, stream>>>(degs, bsum, N);
    scan_bsum<<<1, 1024, 0, stream>>>(bsum, boff, nb);
    scan_final<<<nb, 256, 0, stream>>>(degs, boff, srow, N);
    fill_csr_kernel<<<(E + 255) / 256, 256, 0, stream>>>(src, dst, dis, srow, cnt,
                                                         scol, senorm, E);
    yinit_kernel<<<1, NG, 0, stream>>>(ptr, Ya);

    int sg = (N * 64 + 255) / 256;
    spmm_kernel<<<sg, 256, 0, stream>>>(Ya, srow, scol, senorm, Yb, N);   // Y1
    colsum_kernel<<<64, 256, 0, stream>>>(Yb, cs + 0, N);
    spmm_kernel<<<sg, 256, 0, stream>>>(Yb, srow, scol, senorm, Ya, N);   // Y2
    colsum_kernel<<<64, 256, 0, stream>>>(Ya, cs + 64, N);
    spmm_kernel<<<sg, 256, 0, stream>>>(Ya, srow, scol, senorm, Yb, N);   // Y3
    colsum_kernel<<<64, 256, 0, stream>>>(Yb, cs + 128, N);
    spmm_kernel<<<sg, 256, 0, stream>>>(Yb, srow, scol, senorm, Ya, N);   // Y4

    matsq_kernel<<<16, 256, 0, stream>>>(W, W2);
    matsq_kernel<<<16, 256, 0, stream>>>(W2, W4);
    tvec_kernel<<<1, D, 0, stream>>>(bias, W, T);

    zacc_kernel<<<128, 256, 0, stream>>>(Ya, x, emb, Z, N);
    final_kernel<<<(NG * D + 255) / 256, 256, 0, stream>>>(Z, W4, T, cs, bias,
                                                           (float*)d_out);
}

// Round 6
// 744.335 us; speedup vs baseline: 1.2733x; 1.2733x over previous
//
#include <hip/hip_runtime.h>
#include <hip/hip_bf16.h>

// GCN encoder, reassociated:  out = Y4^T · emb[x] · W^4 + bias terms,
// where Y4 = (A^T)^4 S (S = one-hot columns of the 64 selected nodes).
// R5: zacc restructured — 1 float4 acc/thread (was 8 -> spilled to scratch at VGPR=32,
// 449us, WRITE_SIZE 32MB for a 32KB output). grid = 64 chunks x 4 d-slices, block 512.

#define D 128
#define NG 64   // graphs in batch (B)

// ---- fused degree histograms: degd (by dst, for norm), degs (by src, for CSR) ----
__global__ void hist2_kernel(const int* __restrict__ src, const int* __restrict__ dst,
                             int* __restrict__ degd, int* __restrict__ degs, int E) {
    int e = blockIdx.x * blockDim.x + threadIdx.x;
    if (e < E) { atomicAdd(&degd[dst[e]], 1); atomicAdd(&degs[src[e]], 1); }
}

// ---- deg_inv_sqrt (GCN norm uses in-degree by dst) ----
__global__ void dis_kernel(const int* __restrict__ degd, float* __restrict__ dis, int n) {
    int i = blockIdx.x * blockDim.x + threadIdx.x;
    if (i < n) {
        int d = degd[i];
        dis[i] = (d > 0) ? rsqrtf((float)d) : 0.0f;
    }
}

__device__ __forceinline__ int wave_incl_scan(int v, int lane) {
    #pragma unroll
    for (int off = 1; off < 64; off <<= 1) {
        int t = __shfl_up(v, off);
        if (lane >= off) v += t;
    }
    return v;
}

// ---- 3-stage exclusive scan of degs -> srow_ptr ----
__global__ __launch_bounds__(256) void scan_reduce(const int* __restrict__ deg,
                                                   int* __restrict__ bsum, int n) {
    __shared__ int wsum[4];
    int b = blockIdx.x, tid = threadIdx.x;
    int s = 0;
    for (int j = tid; j < 1024; j += 256) {
        int idx = b * 1024 + j;
        if (idx < n) s += deg[idx];
    }
    #pragma unroll
    for (int off = 32; off; off >>= 1) s += __shfl_down(s, off);
    int lane = tid & 63, wid = tid >> 6;
    if (lane == 0) wsum[wid] = s;
    __syncthreads();
    if (tid == 0) bsum[b] = wsum[0] + wsum[1] + wsum[2] + wsum[3];
}

__global__ void scan_bsum(const int* __restrict__ bsum, int* __restrict__ boff, int nb) {
    __shared__ int buf[1024];
    int tid = threadIdx.x;
    int v = (tid < nb) ? bsum[tid] : 0;
    buf[tid] = v;
    __syncthreads();
    for (int off = 1; off < 1024; off <<= 1) {
        int t = (tid >= off) ? buf[tid - off] : 0;
        __syncthreads();
        buf[tid] += t;
        __syncthreads();
    }
    if (tid < nb) boff[tid] = buf[tid] - v;
}

__global__ __launch_bounds__(256) void scan_final(const int* __restrict__ deg,
                                                  const int* __restrict__ boff,
                                                  int* __restrict__ row_ptr, int n) {
    __shared__ int wsum[4];
    int b = blockIdx.x, tid = threadIdx.x;
    int lane = tid & 63, wid = tid >> 6;
    int base = b * 1024 + tid * 4;
    int v[4], s = 0;
    #pragma unroll
    for (int j = 0; j < 4; j++) {
        int idx = base + j;
        v[j] = (idx < n) ? deg[idx] : 0;
        s += v[j];
    }
    int incl = wave_incl_scan(s, lane);
    if (lane == 63) wsum[wid] = incl;
    __syncthreads();
    int woff = 0;
    for (int w = 0; w < wid; w++) woff += wsum[w];
    int run = incl - s + woff + boff[b];
    #pragma unroll
    for (int j = 0; j < 4; j++) {
        int idx = base + j;
        run += v[j];
        if (idx < n) row_ptr[idx + 1] = run;
    }
    if (b == 0 && tid == 0) row_ptr[0] = 0;
}

// ---- CSR by SRC (for A^T application); neighbor = dst, weight = dis[src]*dis[dst] ----
__global__ void fill_csr_kernel(const int* __restrict__ src, const int* __restrict__ dst,
                                const float* __restrict__ dis, const int* __restrict__ srow,
                                int* __restrict__ cnt, int* __restrict__ scol,
                                float* __restrict__ senorm, int E) {
    int e = blockIdx.x * blockDim.x + threadIdx.x;
    if (e >= E) return;
    int s = src[e], d = dst[e];
    int pos = srow[s] + atomicAdd(&cnt[s], 1);
    scol[pos] = d;
    senorm[pos] = dis[s] * dis[d];
}

// ---- Y0 init: Y[sel_g, g] = 1 (auto-detect int32/int64 ptr) ----
__global__ void yinit_kernel(const int* __restrict__ ptr32, float* __restrict__ Y) {
    int g = threadIdx.x;   // one block of NG threads
    bool is64 = (ptr32[3] == 0);   // hi word of ptr[1] is 0 iff int64 (ptr[1] > 0)
    long long node;
    if (is64) node = ((const long long*)ptr32)[g + 1] - 1;
    else      node = (long long)ptr32[g + 1] - 1;
    Y[node * NG + g] = 1.0f;
}

// ---- Y_{k+1}[u,:] = sum_{e: src=u} norm_e * Y_k[dst_e,:]  (wave/node, lane=g, 2-edge unroll) ----
__global__ __launch_bounds__(256) void spmm_kernel(const float* __restrict__ Yin,
                                                   const int* __restrict__ srow,
                                                   const int* __restrict__ scol,
                                                   const float* __restrict__ senorm,
                                                   float* __restrict__ Yout, int n) {
    int node = (blockIdx.x * blockDim.x + threadIdx.x) >> 6;
    int g = threadIdx.x & 63;
    if (node >= n) return;
    int beg = srow[node], end = srow[node + 1];
    float a0 = 0.f, a1 = 0.f;
    int j = beg;
    for (; j + 1 < end; j += 2) {
        int s0 = scol[j], s1 = scol[j + 1];
        float w0 = senorm[j], w1 = senorm[j + 1];
        a0 += Yin[(size_t)s0 * NG + g] * w0;
        a1 += Yin[(size_t)s1 * NG + g] * w1;
    }
    if (j < end) a0 += Yin[(size_t)scol[j] * NG + g] * senorm[j];
    Yout[(size_t)node * NG + g] = a0 + a1;
}

// ---- cs[g] += sum_i Y[i,g]  (= A^k 1 at selected nodes) ----
__global__ __launch_bounds__(256) void colsum_kernel(const float* __restrict__ Y,
                                                     float* __restrict__ cs, int n) {
    __shared__ float part[4][64];
    int g = threadIdx.x & 63, w = threadIdx.x >> 6;
    float a = 0.f;
    for (int i = blockIdx.x * 4 + w; i < n; i += gridDim.x * 4)
        a += Y[(size_t)i * NG + g];
    part[w][g] = a;
    __syncthreads();
    if (w == 0) atomicAdd(&cs[g], part[0][g] + part[1][g] + part[2][g] + part[3][g]);
}

// ---- Z[g,d] = sum_i Y4[i,g] * emb[x[i], d]
// R5: thread = (g = tid&63, d8 = tid>>6); one float4 acc (4 VGPR, no spill).
// grid.x = node chunks, grid.y = 4 d-slices of 32. Wave reads one 256B Y row
// (lanes = g, coalesced); emb float4 is wave-uniform -> broadcast. ----
__global__ __launch_bounds__(512) void zacc_kernel(const float* __restrict__ Y,
                                                   const int* __restrict__ x,
                                                   const float* __restrict__ emb,
                                                   float* __restrict__ Z, int n) {
    int g = threadIdx.x & 63, d8 = threadIdx.x >> 6;
    int dbase = blockIdx.y * 32 + d8 * 4;
    float4 acc = {0.f, 0.f, 0.f, 0.f};
    int chunk = (n + gridDim.x - 1) / gridDim.x;
    int i0 = blockIdx.x * chunk;
    int i1 = min(n, i0 + chunk);
    for (int i = i0; i < i1; i++) {
        int tok = x[i];                              // block-uniform -> scalar load
        float y = Y[(size_t)i * NG + g];             // coalesced 256B per wave
        float4 v = *(const float4*)(emb + (size_t)tok * D + dbase);  // wave-uniform
        acc.x += y * v.x; acc.y += y * v.y; acc.z += y * v.z; acc.w += y * v.w;
    }
    float* zp = Z + g * D + dbase;
    atomicAdd(zp + 0, acc.x);
    atomicAdd(zp + 1, acc.y);
    atomicAdd(zp + 2, acc.z);
    atomicAdd(zp + 3, acc.w);
}

// ---- C = A*A for 128x128 (grid 16, block computes 8 rows; A staged in LDS) ----
__global__ __launch_bounds__(256) void matsq_kernel(const float* __restrict__ A,
                                                    float* __restrict__ C) {
    __shared__ float Al[D * D];
    int tid = threadIdx.x;
    const float4* A4 = (const float4*)A;
    float4* Al4 = (float4*)Al;
    for (int i = tid; i < D * D / 4; i += 256) Al4[i] = A4[i];
    __syncthreads();
    int r = blockIdx.x * 8 + (tid >> 5);
    int c0 = (tid & 31) * 4;
    float4 acc = {0.f, 0.f, 0.f, 0.f};
    for (int k = 0; k < D; k++) {
        float a = Al[r * D + k];
        float4 w = *(const float4*)&Al[k * D + c0];
        acc.x += a * w.x; acc.y += a * w.y; acc.z += a * w.z; acc.w += a * w.w;
    }
    *(float4*)&C[r * D + c0] = acc;
}

// ---- T[k] = b^T W^{k+1}, k=0..2 (one block, 128 threads) ----
__global__ void tvec_kernel(const float* __restrict__ b, const float* __restrict__ W,
                            float* __restrict__ T) {
    __shared__ float cur[D];
    int tid = threadIdx.x;
    cur[tid] = b[tid];
    __syncthreads();
    for (int it = 0; it < 3; it++) {
        float acc = 0.f;
        for (int k = 0; k < D; k++) acc += cur[k] * W[k * D + tid];
        __syncthreads();
        cur[tid] = acc;
        T[it * D + tid] = acc;
        __syncthreads();
    }
}

// ---- out[g,d] = (Z*W4)[g,d] + cs1[g]*T1[d] + cs2[g]*T2[d] + cs3[g]*T3[d] + b[d] ----
__global__ __launch_bounds__(256) void final_kernel(const float* __restrict__ Z,
                                                    const float* __restrict__ W4,
                                                    const float* __restrict__ T,
                                                    const float* __restrict__ cs,
                                                    const float* __restrict__ b,
                                                    float* __restrict__ out) {
    int o = blockIdx.x * blockDim.x + threadIdx.x;
    if (o >= NG * D) return;
    int g = o >> 7, d = o & (D - 1);
    float acc = b[d];
    for (int k = 0; k < D; k++) acc += Z[g * D + k] * W4[k * D + d];
    acc += cs[g] * T[d] + cs[64 + g] * T[D + d] + cs[128 + g] * T[2 * D + d];
    out[o] = acc;
}

extern "C" void kernel_launch(void* const* d_in, const int* in_sizes, int n_in,
                              void* d_out, int out_size, void* d_ws, size_t ws_size,
                              hipStream_t stream) {
    const int*   x    = (const int*)d_in[0];
    const int*   ei   = (const int*)d_in[1];
    const int*   ptr  = (const int*)d_in[2];   // width auto-detected on device
    const float* emb  = (const float*)d_in[4];
    const float* W    = (const float*)d_in[5];
    const float* bias = (const float*)d_in[6];

    const int N = in_sizes[0];
    const int E = in_sizes[1] / 2;

    const int* src = ei;
    const int* dst = ei + E;

    char* ws = (char*)d_ws;
    size_t off = 0;
    auto carve = [&](size_t bytes) -> void* {
        void* p = ws + off;
        off += (bytes + 255) & ~(size_t)255;
        return p;
    };
    float* Ya     = (float*)carve((size_t)N * NG * 4);
    float* Yb     = (float*)carve((size_t)N * NG * 4);
    int*   degd   = (int*)  carve((size_t)N * 4 * 2);   // degd + degs adjacent (one memset)
    int*   degs   = degd + N;
    float* dis    = (float*)carve((size_t)N * 4);
    int*   srow   = (int*)  carve((size_t)(N + 1) * 4);
    int*   cnt    = (int*)  carve((size_t)N * 4);
    int*   scol   = (int*)  carve((size_t)E * 4);
    float* senorm = (float*)carve((size_t)E * 4);
    int    nb     = (N + 1023) / 1024;
    int*   bsum   = (int*)  carve((size_t)nb * 4);
    int*   boff   = (int*)  carve((size_t)nb * 4);
    float* Z      = (float*)carve((size_t)NG * D * 4);  // 32768 B (256-aligned)
    float* cs     = (float*)carve((size_t)3 * NG * 4);  // adjacent to Z
    float* W2     = (float*)carve((size_t)D * D * 4);
    float* W4     = (float*)carve((size_t)D * D * 4);
    float* T      = (float*)carve((size_t)3 * D * 4);

    hipMemsetAsync(degd, 0, (size_t)N * 4 * 2, stream);
    hipMemsetAsync(cnt,  0, (size_t)N * 4, stream);
    hipMemsetAsync(Ya,   0, (size_t)N * NG * 4, stream);
    hipMemsetAsync(Z,    0, (size_t)(NG * D + 3 * NG) * 4, stream);  // Z + cs contiguous

    hist2_kernel<<<(E + 255) / 256, 256, 0, stream>>>(src, dst, degd, degs, E);
    dis_kernel<<<(N + 255) / 256, 256, 0, stream>>>(degd, dis, N);
    scan_reduce<<<nb, 256, 0, stream>>>(degs, bsum, N);
    scan_bsum<<<1, 1024, 0, stream>>>(bsum, boff, nb);
    scan_final<<<nb, 256, 0, stream>>>(degs, boff, srow, N);
    fill_csr_kernel<<<(E + 255) / 256, 256, 0, stream>>>(src, dst, dis, srow, cnt,
                                                         scol, senorm, E);
    yinit_kernel<<<1, NG, 0, stream>>>(ptr, Ya);

    int sg = (N * 64 + 255) / 256;
    spmm_kernel<<<sg, 256, 0, stream>>>(Ya, srow, scol, senorm, Yb, N);   // Y1
    colsum_kernel<<<64, 256, 0, stream>>>(Yb, cs + 0, N);
    spmm_kernel<<<sg, 256, 0, stream>>>(Yb, srow, scol, senorm, Ya, N);   // Y2
    colsum_kernel<<<64, 256, 0, stream>>>(Ya, cs + 64, N);
    spmm_kernel<<<sg, 256, 0, stream>>>(Ya, srow, scol, senorm, Yb, N);   // Y3
    colsum_kernel<<<64, 256, 0, stream>>>(Yb, cs + 128, N);
    spmm_kernel<<<sg, 256, 0, stream>>>(Yb, srow, scol, senorm, Ya, N);   // Y4

    matsq_kernel<<<16, 256, 0, stream>>>(W, W2);
    matsq_kernel<<<16, 256, 0, stream>>>(W2, W4);
    tvec_kernel<<<1, D, 0, stream>>>(bias, W, T);

    dim3 zgrid(64, 4);
    zacc_kernel<<<zgrid, 512, 0, stream>>>(Ya, x, emb, Z, N);
    final_kernel<<<(NG * D + 255) / 256, 256, 0, stream>>>(Z, W4, T, cs, bias,
                                                           (float*)d_out);
}